// Round 5
// baseline (772.566 us; speedup 1.0000x reference)
//
#include <hip/hip_runtime.h>
#include <hip/hip_bf16.h>
#include <math.h>

#define DI __device__ __forceinline__

typedef unsigned short u16;
typedef unsigned int   u32;
typedef unsigned long long u64;
typedef __attribute__((ext_vector_type(8))) short short8;   // 8 bf16 (4 VGPRs) MFMA A/B frag
typedef __attribute__((ext_vector_type(4))) float f32x4;    // MFMA C/D frag

constexpr int CB = 512;    // channels
constexpr int LL = 4096;   // length
constexpr int NG = 32;     // groups

DI float bf2f(u16 u) { u32 v = ((u32)u) << 16; float f; __builtin_memcpy(&f, &v, 4); return f; }
DI u16 f2bf(float f) {
  u32 u; __builtin_memcpy(&u, &f, 4);
  u += 0x7fffu + ((u >> 16) & 1u);   // RNE
  return (u16)(u >> 16);
}

DI void gload16(const void* g, void* l) {
  __builtin_amdgcn_global_load_lds((const __attribute__((address_space(1))) u32*)g,
                                   (__attribute__((address_space(3))) u32*)l, 16, 0, 0);
}

// ---------------------------------------------------------------------------
// K0: weights -> bf16 (wqkv fused [1536][512], wo [512][512]); fused bias.
// ---------------------------------------------------------------------------
__global__ __launch_bounds__(256) void conv_w(
    const float* __restrict__ wq, const float* __restrict__ wk,
    const float* __restrict__ wv, const float* __restrict__ wo,
    const float* __restrict__ bq, const float* __restrict__ bk,
    const float* __restrict__ bv,
    u16* __restrict__ wqkv, u16* __restrict__ wob, float* __restrict__ bqkv) {
  if (blockIdx.x < 1024) {
    int i = blockIdx.x * 256 + threadIdx.x;
    wqkv[i]          = f2bf(wq[i]);
    wqkv[262144 + i] = f2bf(wk[i]);
    wqkv[524288 + i] = f2bf(wv[i]);
    wob[i]           = f2bf(wo[i]);
  } else {
    for (int j = 0; j < 6; ++j) {
      int idx = j * 256 + threadIdx.x;
      float b = (idx < 512) ? bq[idx] : (idx < 1024) ? bk[idx - 512] : bv[idx - 1024];
      bqkv[idx] = b;
    }
  }
}

// ---------------------------------------------------------------------------
// K1: GroupNorm stats. One block per (b,g).
// ---------------------------------------------------------------------------
__global__ __launch_bounds__(256) void gn_stats(const float* __restrict__ x,
                                                float* __restrict__ stats) {
  const float4* base = (const float4*)(x + (long)blockIdx.x * (16 * LL));
  float s = 0.f, ss = 0.f;
  for (int i = threadIdx.x; i < 16 * LL / 4; i += 256) {
    float4 v = base[i];
    s  += v.x + v.y + v.z + v.w;
    ss += v.x * v.x + v.y * v.y + v.z * v.z + v.w * v.w;
  }
#pragma unroll
  for (int o = 32; o; o >>= 1) { s += __shfl_xor(s, o); ss += __shfl_xor(ss, o); }
  __shared__ float red[8];
  int wv = threadIdx.x >> 6, ln = threadIdx.x & 63;
  if (ln == 0) { red[wv * 2] = s; red[wv * 2 + 1] = ss; }
  __syncthreads();
  if (threadIdx.x == 0) {
    float S = red[0] + red[2] + red[4] + red[6];
    float SS = red[1] + red[3] + red[5] + red[7];
    float mu = S * (1.f / 65536.f);
    float var = SS * (1.f / 65536.f) - mu * mu;
    stats[blockIdx.x * 2]     = mu;
    stats[blockIdx.x * 2 + 1] = rsqrtf(var + 1e-6f);
  }
}

// ---------------------------------------------------------------------------
// K2: GroupNorm apply + transpose: hT[b][l][c] = bf16(gn(x[b][c][l]))
// ---------------------------------------------------------------------------
__global__ __launch_bounds__(256) void gn_apply(
    const float* __restrict__ x, const float* __restrict__ gw,
    const float* __restrict__ gb, const float* __restrict__ stats,
    u16* __restrict__ hT) {
  __shared__ u16 t[64][66];
  const int b = blockIdx.z, c0 = blockIdx.y * 64, l0 = blockIdx.x * 64;
  const int ln = threadIdx.x & 63, sub = threadIdx.x >> 6;
  for (int cr = sub; cr < 64; cr += 4) {
    int c = c0 + cr;
    float v  = x[(long)b * CB * LL + (long)c * LL + l0 + ln];
    float mu = stats[(b * NG + (c >> 4)) * 2];
    float rs = stats[(b * NG + (c >> 4)) * 2 + 1];
    t[cr][ln] = f2bf((v - mu) * rs * gw[c] + gb[c]);
  }
  __syncthreads();
  for (int lr = sub; lr < 64; lr += 4)
    hT[(long)b * LL * CB + (long)(l0 + lr) * CB + c0 + ln] = t[ln][lr];
}

// ---------------------------------------------------------------------------
// Shared GEMM skeleton: D[M][N] = A[M][K] * Bt[N][K]^T  (both k-contiguous)
// BK=64, 4 waves (2x2), 16x16x32 bf16 MFMA, LDS XOR-swizzled staging
// (linear global_load_lds dest + pre-swizzled global source — rule #21).
// EPI: 0=QKV (q,k,v ALL stored transposed [l][c]; +bias)
//      1/2=bf16 row-major tile store via LDS repack (1 applies *scale)
//      3=fused attn-out (fp32 +bias +residual: out = A*Bt^T + bias + xres)
// SWZ: bijective XCD-chunked blockIdx swizzle (requires nwg%8==0).
// ---------------------------------------------------------------------------
template <int BM, int BN, int EPI, bool SWZ>
__global__ __launch_bounds__(256) void gemm_bt(
    const u16* __restrict__ A, int lda, long asb,
    const u16* __restrict__ Bt, int ldb, long bsb,
    int K, const float* __restrict__ bias, float scale,
    u16* __restrict__ o0, u16* __restrict__ o1, u16* __restrict__ o2,
    float* __restrict__ of, const float* __restrict__ xres, long osb, int ldo) {
  constexpr int FM = BM / 32, FN = BN / 32;
  __shared__ u16 smem[(BM + BN) * 64];
  u16* lA = smem;
  u16* lB = smem + BM * 64;

  int bx = blockIdx.x, by = blockIdx.y;
  if constexpr (SWZ) {
    const int nwg = gridDim.x * gridDim.y;
    const int id = by * gridDim.x + bx;
    const int id2 = (id & 7) * (nwg >> 3) + (id >> 3);
    bx = id2 % gridDim.x;
    by = id2 / gridDim.x;
  }

  const int tid = threadIdx.x;
  const int lane = tid & 63;
  const int wv = tid >> 6;
  const int wr = wv >> 1, wc = wv & 1;
  const int fr = lane & 15, fq = lane >> 4;
  const int bz = blockIdx.z;

  const u16* Ab = A + (long)bz * asb + (long)(by * BM) * lda;
  const u16* Bb = Bt + (long)bz * bsb + (long)(bx * BN) * ldb;

  f32x4 acc[FM][FN];
#pragma unroll
  for (int m = 0; m < FM; ++m)
#pragma unroll
    for (int n = 0; n < FN; ++n) acc[m][n] = (f32x4)(0.f);

  for (int k0 = 0; k0 < K; k0 += 64) {
#pragma unroll
    for (int p = 0; p < BM / 32; ++p) {
      int t = p * 256 + tid;
      int row = t >> 3;
      int cbl = ((t & 7) << 4) ^ ((row & 7) << 4);     // inverse-swizzled source col (bytes)
      gload16(Ab + (long)row * lda + k0 + (cbl >> 1), &lA[t * 8]);
    }
#pragma unroll
    for (int p = 0; p < BN / 32; ++p) {
      int t = p * 256 + tid;
      int row = t >> 3;
      int cbl = ((t & 7) << 4) ^ ((row & 7) << 4);
      gload16(Bb + (long)row * ldb + k0 + (cbl >> 1), &lB[t * 8]);
    }
    __syncthreads();
#pragma unroll
    for (int ks = 0; ks < 2; ++ks) {
      short8 af[FM], bfr[FN];
#pragma unroll
      for (int m = 0; m < FM; ++m) {
        int row = wr * (BM / 2) + m * 16 + fr;
        int cb = (ks * 64 + fq * 16) ^ ((row & 7) << 4);
        af[m] = *(const short8*)((const char*)lA + row * 128 + cb);
      }
#pragma unroll
      for (int n = 0; n < FN; ++n) {
        int row = wc * (BN / 2) + n * 16 + fr;
        int cb = (ks * 64 + fq * 16) ^ ((row & 7) << 4);
        bfr[n] = *(const short8*)((const char*)lB + row * 128 + cb);
      }
#pragma unroll
      for (int m = 0; m < FM; ++m)
#pragma unroll
        for (int n = 0; n < FN; ++n)
          acc[m][n] = __builtin_amdgcn_mfma_f32_16x16x32_bf16(af[m], bfr[n], acc[m][n], 0, 0, 0);
    }
    __syncthreads();
  }

  const int ml0 = wr * (BM / 2);
  const int nl0 = wc * (BN / 2);

  if constexpr (EPI == 3) {
    // fused attention-out: fp32 = acc + bias[m] + xres
    const int mg0 = by * BM + ml0;
    const int ng0 = bx * BN + nl0;
#pragma unroll
    for (int m = 0; m < FM; ++m)
#pragma unroll
      for (int n = 0; n < FN; ++n) {
        const int ng = ng0 + n * 16 + fr;
#pragma unroll
        for (int r = 0; r < 4; ++r) {
          const int mg = mg0 + m * 16 + fq * 4 + r;
          const long off = (long)bz * osb + (long)mg * ldo + ng;
          of[off] = acc[m][n][r] + bias[mg] + xres[off];
        }
      }
  } else if constexpr (EPI == 0) {
    // QKV: all three outputs stored transposed [l][c].  by in [0,12): mat=by>>2
    const int mat = by >> 2;
    u16* pl = (mat == 0) ? o0 : (mat == 1) ? o1 : o2;
#pragma unroll
    for (int m = 0; m < FM; ++m)
#pragma unroll
      for (int n = 0; n < FN; ++n) {
        const int nl = nl0 + n * 16 + fr;
#pragma unroll
        for (int r = 0; r < 4; ++r) {
          const int ml = ml0 + m * 16 + fq * 4 + r;
          smem[nl * BM + (ml ^ ((nl & 7) << 3))] =
              f2bf(acc[m][n][r] + bias[by * BM + ml]);
        }
      }
    __syncthreads();
    u16* dst0 = pl + (long)bz * ((long)LL * CB) +
                (long)(bx * BN) * CB + ((by * BM) & 511);
    for (int i = tid * 8; i < BM * BN; i += 2048) {
      const int rr = i / BM, cc = i % BM;
      short8 val = *(const short8*)&smem[rr * BM + (cc ^ ((rr & 7) << 3))];
      *(short8*)(dst0 + (long)rr * CB + cc) = val;
    }
  } else {
    // EPI 1/2: row-major [m][n] bf16 tile (scaled for EPI 1)
#pragma unroll
    for (int m = 0; m < FM; ++m)
#pragma unroll
      for (int n = 0; n < FN; ++n) {
        const int nl = nl0 + n * 16 + fr;
#pragma unroll
        for (int r = 0; r < 4; ++r) {
          const int ml = ml0 + m * 16 + fq * 4 + r;
          smem[ml * BN + (nl ^ ((ml & 7) << 3))] = f2bf(acc[m][n][r] * scale);
        }
      }
    __syncthreads();
    u16* dst0 = o0 + (long)bz * osb + (long)(by * BM) * ldo + bx * BN;
    for (int i = tid * 8; i < BM * BN; i += 2048) {
      const int rr = i / BN, cc = i % BN;
      short8 val = *(const short8*)&smem[rr * BN + (cc ^ ((rr & 7) << 3))];
      *(short8*)(dst0 + (long)rr * ldo + cc) = val;
    }
  }
}

// ---------------------------------------------------------------------------
// K4: row softmax in-place on bf16 S [G][4096][4096]; block = one row.
// ---------------------------------------------------------------------------
__global__ __launch_bounds__(256) void softmax_row(u16* __restrict__ S) {
  u16* row = S + ((long)blockIdx.y * LL + blockIdx.x) * LL;
  const int tid = threadIdx.x;
  const int wv = tid >> 6, ln = tid & 63;
  short8 a = ((const short8*)row)[tid * 2];
  short8 b = ((const short8*)row)[tid * 2 + 1];
  float v[16];
#pragma unroll
  for (int j = 0; j < 8; ++j) { v[j] = bf2f((u16)a[j]); v[8 + j] = bf2f((u16)b[j]); }
  float mx = -1e30f;
#pragma unroll
  for (int j = 0; j < 16; ++j) mx = fmaxf(mx, v[j]);
#pragma unroll
  for (int o = 32; o; o >>= 1) mx = fmaxf(mx, __shfl_xor(mx, o));
  __shared__ float red[4];
  if (ln == 0) red[wv] = mx;
  __syncthreads();
  mx = fmaxf(fmaxf(red[0], red[1]), fmaxf(red[2], red[3]));
  __syncthreads();
  float sum = 0.f;
#pragma unroll
  for (int j = 0; j < 16; ++j) { v[j] = __expf(v[j] - mx); sum += v[j]; }
#pragma unroll
  for (int o = 32; o; o >>= 1) sum += __shfl_xor(sum, o);
  if (ln == 0) red[wv] = sum;
  __syncthreads();
  sum = red[0] + red[1] + red[2] + red[3];
  const float r = 1.f / sum;
  short8 o1, o2;
#pragma unroll
  for (int j = 0; j < 8; ++j) { o1[j] = (short)f2bf(v[j] * r); o2[j] = (short)f2bf(v[8 + j] * r); }
  ((short8*)row)[tid * 2] = o1;
  ((short8*)row)[tid * 2 + 1] = o2;
}

// ---------------------------------------------------------------------------
extern "C" void kernel_launch(void* const* d_in, const int* in_sizes, int n_in,
                              void* d_out, int out_size, void* d_ws, size_t ws_size,
                              hipStream_t stream) {
  const float* x   = (const float*)d_in[0];
  const float* gnw = (const float*)d_in[1];
  const float* gnb = (const float*)d_in[2];
  const float* wq  = (const float*)d_in[3];
  const float* bq  = (const float*)d_in[4];
  const float* wk  = (const float*)d_in[5];
  const float* bk  = (const float*)d_in[6];
  const float* wv  = (const float*)d_in[7];
  const float* bv  = (const float*)d_in[8];
  const float* wo  = (const float*)d_in[9];
  const float* bo  = (const float*)d_in[10];
  float* out = (float*)d_out;

  char* ws = (char*)d_ws;
  const long NEL = (long)LL * CB;          // 2M elems = 4 MB bf16 per batch-plane
  const long SEL = (long)LL * LL;          // 16M elems = 32 MB bf16 per batch S
  float* stats = (float*)ws;                               // 8 KB
  float* bqkv  = (float*)(ws + 8192);                      // 6 KB
  u16* wqkv = (u16*)(ws + 16384);                          // 1.5 MB
  u16* wob  = (u16*)(ws + 16384 + 1572864);                // 0.5 MB
  u16* hT   = (u16*)(ws + (4l << 20));                     // 32 MB  [B][L][C]; = W after QKV
  u16* qT   = hT + 8 * NEL;                                // 32 MB  [B][L][C]
  u16* kT   = qT + 8 * NEL;                                // 32 MB  [B][L][C]
  u16* vT   = kT + 8 * NEL;                                // 32 MB  [B][L][C] (transposed now)
  u16* W    = hT;                                          // W[b][o][j], hT dead after QKV
  const size_t base = (4ul << 20) + 4ul * 8 * NEL * 2;     // 132 MB
  u16* Sbuf = (u16*)(ws + base);

  const int G = (ws_size >= base + 2ul * SEL * 2) ? 2 : 1;

  conv_w<<<1025, 256, 0, stream>>>(wq, wk, wv, wo, bq, bk, bv, wqkv, wob, bqkv);
  gn_stats<<<256, 256, 0, stream>>>(x, stats);
  gn_apply<<<dim3(64, 8, 8), 256, 0, stream>>>(x, gnw, gnb, stats, hT);

  // fused QKV: A=wqkv [1536][512], Bt=hT[b] [4096][512]; q,k,v all -> [l][c]
  gemm_bt<128, 128, 0, false><<<dim3(32, 12, 8), 256, 0, stream>>>(
      wqkv, 512, 0, hT, 512, NEL, 512, bqkv, 1.f, qT, kT, vT, nullptr, nullptr, 0, 0);

  // W[b] = wo * v[b]: A=wob [512][512], Bt=vT[b] [4096][512]; M=512 N=4096 K=512
  gemm_bt<128, 128, 2, false><<<dim3(32, 4, 8), 256, 0, stream>>>(
      wob, 512, 0, vT, 512, NEL, 512, nullptr, 1.f,
      W, nullptr, nullptr, nullptr, nullptr, NEL, LL);

  const float scal = 1.0f / sqrtf(512.0f);
  for (int g0 = 0; g0 < 8; g0 += G) {
    // S[z] = scale * qT[g0+z] * kT[g0+z]^T : M=N=4096, K=512
    gemm_bt<128, 128, 1, true><<<dim3(32, 32, G), 256, 0, stream>>>(
        qT + (long)g0 * NEL, 512, NEL, kT + (long)g0 * NEL, 512, NEL, 512,
        nullptr, scal, Sbuf, nullptr, nullptr, nullptr, nullptr, SEL, LL);
    softmax_row<<<dim3(LL, G), 256, 0, stream>>>(Sbuf);
    // out[g][o][i] = x + bo[o] + sum_j W[g][o][j] P[i][j] : M=512 N=4096 K=4096
    gemm_bt<64, 128, 3, true><<<dim3(32, 8, G), 256, 0, stream>>>(
        W + (long)g0 * NEL, LL, NEL, Sbuf, LL, SEL, LL, bo, 1.f,
        nullptr, nullptr, nullptr, out + (long)g0 * NEL, x + (long)g0 * NEL, NEL, LL);
  }

  (void)in_sizes; (void)n_in; (void)out_size; (void)ws_size;
}